// Round 21
// baseline (267.617 us; speedup 1.0000x reference)
//
#include <hip/hip_runtime.h>
#include <hip/hip_bf16.h>

typedef __bf16 bf16;
typedef __bf16 bf16x8 __attribute__((ext_vector_type(8)));
typedef __bf16 bf16x4 __attribute__((ext_vector_type(4)));
typedef float f32x4 __attribute__((ext_vector_type(4)));
typedef unsigned int u32x2 __attribute__((ext_vector_type(2)));
typedef unsigned int u32x4 __attribute__((ext_vector_type(4)));

#define MFMA16(a,b,c) __builtin_amdgcn_mfma_f32_16x16x32_bf16(a,b,c,0,0,0)
#define EXP2(x) __builtin_amdgcn_exp2f(x)   // raw v_exp_f32 (1 ULP), no libm guard code

// async global->LDS, 16B per lane; LDS dest = wave-uniform base + lane*16
static __device__ __forceinline__ void gll16(const void* g, void* l) {
    __builtin_amdgcn_global_load_lds(
        (const __attribute__((address_space(1))) void*)g,
        (__attribute__((address_space(3))) void*)l, 16, 0, 0);
}

// ---------------- convert x (fp32 -> bf16) ----------------
__global__ void k_cvt(const float* __restrict__ in, bf16* __restrict__ out, int n4) {
    int i = blockIdx.x * 256 + threadIdx.x;
    if (i < n4) {
        float4 v = ((const float4*)in)[i];
        bf16x4 o = { (bf16)v.x, (bf16)v.y, (bf16)v.z, (bf16)v.w };
        *(bf16x4*)(out + (long)i * 4) = o;
    }
}

// ---------------- transpose fp32 [R][C] -> bf16 [C][R] ----------------
__global__ void k_transpose(const float* __restrict__ in, bf16* __restrict__ out, int R, int C) {
    __shared__ float t[32][33];
    int c0 = blockIdx.x * 32, r0 = blockIdx.y * 32;
    int tx = threadIdx.x, ty = threadIdx.y; // 32 x 8
    for (int j = 0; j < 4; ++j)
        t[ty + 8 * j][tx] = in[(long)(r0 + ty + 8 * j) * C + c0 + tx];
    __syncthreads();
    for (int j = 0; j < 4; ++j)
        out[(long)(c0 + ty + 8 * j) * R + r0 + tx] = (bf16)t[tx][ty + 8 * j];
}

// ---------------- transpose V bf16 [BH][4096][64] -> [BH][64][4096] ----------------
__global__ void k_transpose_v(const bf16* __restrict__ in, bf16* __restrict__ out) {
    __shared__ bf16 t[64][72];
    int bh = blockIdx.x >> 6, s0 = (blockIdx.x & 63) * 64;
    int tid = threadIdx.x;
    int r = tid >> 3, c8 = (tid & 7) * 8;
    const bf16* ip = in + ((long)bh * 4096 + s0) * 64;
    *(bf16x8*)&t[r][c8]      = *(const bf16x8*)(ip + (long)r * 64 + c8);
    *(bf16x8*)&t[r + 32][c8] = *(const bf16x8*)(ip + (long)(r + 32) * 64 + c8);
    __syncthreads();
    bf16* op = out + (long)bh * 64 * 4096 + s0;
    #pragma unroll
    for (int it = 0; it < 2; ++it) {
        int d = r + it * 32;
        bf16x8 v;
        #pragma unroll
        for (int j = 0; j < 8; ++j) v[j] = t[c8 + j][d];
        *(bf16x8*)(op + (long)d * 4096 + c8) = v;
    }
}

// ---------------- GEMM C = A * B^T (global_load_lds staging, m97-style) ----------------
// Linear LDS [2][128][32] per operand, XOR-swizzled chunks: xs(row)=(row&3)^((row>>2)&3),
// swizzle applied on the GLOBAL source (rule 21), fragment reads use the same xs.
// MODE 0: QKV epilogue -> Qg (scaled 0.125*log2e), Kg, Vg all [B,H,S,D] coalesced.
// MODE 1: out epilogue (bias, fp32 row-major).
template <int MODE>
__launch_bounds__(256)
__global__ void k_gemm_bt(const bf16* __restrict__ A, const bf16* __restrict__ BT, int K,
                          const float* __restrict__ bias,
                          bf16* __restrict__ Qg, bf16* __restrict__ Kg, bf16* __restrict__ Vg,
                          float* __restrict__ Out) {
    __shared__ __align__(16) char As[2][8192];   // [buf][128 rows x 32 bf16]
    __shared__ __align__(16) char Bs[2][8192];
    int tid = threadIdx.x;
    int w = tid >> 6, lane = tid & 63;
    int m0 = blockIdx.y * 128, n0 = blockIdx.x * 128;
    int wm = (w >> 1) * 64, wn = (w & 1) * 64;
    f32x4 acc[4][4] = {};
    int la = lane & 15, g4 = lane >> 4, g8 = g4 * 8;

    // staging: gll #1 covers rows 0-63 (wave w: rows 16w..16w+15), #2 rows 64-127
    int srow = w * 16 + (lane >> 2);
    int xsw = (srow & 3) ^ ((srow >> 2) & 3);     // same for srow and srow+64
    int csrc = ((lane & 3) ^ xsw) * 8;            // pre-swizzled source chunk (elems)
    const bf16* apg  = A  + (long)(m0 + srow) * K + csrc;
    const bf16* apg2 = A  + (long)(m0 + 64 + srow) * K + csrc;
    const bf16* bpg  = BT + (long)(n0 + srow) * K + csrc;
    const bf16* bpg2 = BT + (long)(n0 + 64 + srow) * K + csrc;
    int ldst = tid * 16;                          // linear dest (= w*1024 + lane*16)

    // fragment read chunk offset: xs depends only on la (row = wm + i*16 + la)
    int xs = (la & 3) ^ ((la >> 2) & 3);
    int cofs = ((g4 ^ xs) << 4);

    // preload slab 0 into buf 0
    gll16(apg,  As[0] + ldst);
    gll16(apg2, As[0] + 4096 + ldst);
    gll16(bpg,  Bs[0] + ldst);
    gll16(bpg2, Bs[0] + 4096 + ldst);
    __syncthreads();

    int cur = 0;
    for (int kk = 0; kk < K; kk += 32) {
        bool more = (kk + 32) < K;
        if (more) {
            gll16(apg + kk + 32,  As[cur ^ 1] + ldst);
            gll16(apg2 + kk + 32, As[cur ^ 1] + 4096 + ldst);
            gll16(bpg + kk + 32,  Bs[cur ^ 1] + ldst);
            gll16(bpg2 + kk + 32, Bs[cur ^ 1] + 4096 + ldst);
        }
        bf16x8 af[4], bfv[4];
        #pragma unroll
        for (int i = 0; i < 4; ++i)
            af[i] = *(const bf16x8*)(As[cur] + (wm + i * 16 + la) * 64 + cofs);
        #pragma unroll
        for (int i = 0; i < 4; ++i)
            bfv[i] = *(const bf16x8*)(Bs[cur] + (wn + i * 16 + la) * 64 + cofs);
        #pragma unroll
        for (int i = 0; i < 4; ++i)
            #pragma unroll
            for (int j = 0; j < 4; ++j)
                acc[i][j] = MFMA16(af[i], bfv[j], acc[i][j]);
        __syncthreads();   // drains vmcnt -> next buffer complete
        cur ^= 1;
    }

    for (int j = 0; j < 4; ++j) {
        int n = n0 + wn + j * 16 + la;
        float bb = bias[n];
        if (MODE == 0) {
            int which = n >> 10, e = n & 1023, h = e >> 6, d = e & 63;
            for (int i = 0; i < 4; ++i) {
                int mbase = m0 + wm + i * 16 + g4 * 4;
                for (int r = 0; r < 4; ++r) {
                    int m = mbase + r;
                    float v = acc[i][j][r] + bb;
                    int b = m >> 12, s = m & 4095;
                    long bhh = (long)(b * 16 + h);
                    if (which == 0)      Qg[(bhh * 4096 + s) * 64 + d] = (bf16)(v * 0.18033688f); // 0.125*log2e
                    else if (which == 1) Kg[(bhh * 4096 + s) * 64 + d] = (bf16)v;
                    else                 Vg[(bhh * 4096 + s) * 64 + d] = (bf16)v;
                }
            }
        } else {
            for (int i = 0; i < 4; ++i) {
                int mbase = m0 + wm + i * 16 + g4 * 4;
                for (int r = 0; r < 4; ++r)
                    Out[(long)(mbase + r) * 1024 + n] = acc[i][j][r] + bb;
            }
        }
    }
}

// ---------------- flash attention (round-20-identical) ----------------
__launch_bounds__(256, 4)
__global__ void k_attn(const bf16* __restrict__ Qg, const bf16* __restrict__ Kg,
                       const bf16* __restrict__ Vt, bf16* __restrict__ Ob) {
    __shared__ __align__(16) char lds[32768];   // [2 bufs][K 8KB | V 8KB]
    __shared__ __align__(16) bf16 Pl[4][16][64];
    int wg = blockIdx.x;
    int swz = (wg & 7) * 128 + (wg >> 3);       // bijective: 1024 = 8*128
    int bh = swz >> 5, qt = swz & 31;
    int tid = threadIdx.x, w = tid >> 6, lane = tid & 63;
    int la16 = lane & 15, g4 = lane >> 4, g8 = g4 * 8;

    const bf16* Kbase = Kg + (long)bh * 4096 * 64;
    const bf16* Vbase = Vt + (long)bh * 64 * 4096;
    const bf16* Qp = Qg + ((long)bh * 4096 + qt * 128 + w * 32 + la16) * 64;
    bf16x8 qA0 = *(const bf16x8*)(Qp + g8);
    bf16x8 qA1 = *(const bf16x8*)(Qp + 32 + g8);
    bf16x8 qB0 = *(const bf16x8*)(Qp + 1024 + g8);
    bf16x8 qB1 = *(const bf16x8*)(Qp + 1024 + 32 + g8);

    int srow = tid >> 3, sc = tid & 7;
    int csw = sc ^ (srow & 7);
    const bf16* kg = Kbase + (long)srow * 64 + csw * 8;
    const bf16* vg = Vbase + (long)srow * 4096 + csw * 8;
    int wseg = w * 1024;

    int x7 = la16 & 7;
    int bit3 = la16 >> 3;
    int hsw = bit3 * 4;              // element offset of even-kb half within its chunk
    int cA = (g4 ^ x7) << 4;
    int cB = ((4 + g4) ^ x7) << 4;

    const bf16 one = (bf16)1.0f;
    bf16x8 ones = { one, one, one, one, one, one, one, one };

    // P store addresses (one b64 per n): kb = 4n+g4 -> chunk (2n+(g4>>1))^x7, half (g4&1)^bit3
    int pwa[4];
    #pragma unroll
    for (int n = 0; n < 4; ++n)
        pwa[n] = la16 * 64 + (((2 * n + (g4 >> 1)) ^ x7) << 3) + ((g4 & 1) ^ bit3) * 4;
    bf16* pwr = &Pl[w][0][0];
    int prb0 = la16 * 64 + ((g4 ^ x7) << 3);
    int prb1 = la16 * 64 + (((4 + g4) ^ x7) << 3);

    f32x4 o0[4] = {}, o1[4] = {};
    f32x4 ls0 = {}, ls1 = {};

    gll16(kg, lds + wseg);
    gll16(kg + 2048, lds + 4096 + wseg);
    gll16(vg, lds + 8192 + wseg);
    gll16(vg + 131072, lds + 12288 + wseg);
    __syncthreads();

    int cur = 0;
    for (int kv0 = 0; kv0 < 4096; kv0 += 64) {
        bool more = (kv0 + 64) < 4096;
        if (more) {
            char* dbuf = lds + (cur ^ 1) * 16384;
            long kOff = (long)(kv0 + 64) * 64;
            gll16(kg + kOff, dbuf + wseg);
            gll16(kg + kOff + 2048, dbuf + 4096 + wseg);
            gll16(vg + (kv0 + 64), dbuf + 8192 + wseg);
            gll16(vg + (kv0 + 64) + 131072, dbuf + 12288 + wseg);
        }
        const char* kb = lds + cur * 16384;
        const char* vbp = kb + 8192;

        // Phase A: S^T = K x Q^T for both sub-blocks (each K fragment read once)
        f32x4 t0[4] = {}, t1[4] = {};
        __builtin_amdgcn_s_setprio(1);
        #pragma unroll
        for (int n = 0; n < 4; ++n) {
            int row = (n * 16 + la16) * 128;
            bf16x8 k0 = *(const bf16x8*)(kb + row + cA);
            bf16x8 k1 = *(const bf16x8*)(kb + row + cB);
            t0[n] = MFMA16(k0, qA0, t0[n]);
            t0[n] = MFMA16(k1, qA1, t0[n]);
            t1[n] = MFMA16(k0, qB0, t1[n]);
            t1[n] = MFMA16(k1, qB1, t1[n]);
        }
        __builtin_amdgcn_s_setprio(0);

        // Phase B: P = exp2(s) (raw v_exp_f32) -> one b64 store per n; frags via two b64 reads
        #pragma unroll
        for (int n = 0; n < 4; ++n) {
            bf16x4 pk = { (bf16)EXP2(t0[n][0]), (bf16)EXP2(t0[n][1]),
                          (bf16)EXP2(t0[n][2]), (bf16)EXP2(t0[n][3]) };
            *(bf16x4*)(pwr + pwa[n]) = pk;
        }
        u32x2 e0 = *(const u32x2*)(pwr + prb0 + hsw);
        u32x2 d0 = *(const u32x2*)(pwr + prb0 + 4 - hsw);
        u32x2 e1 = *(const u32x2*)(pwr + prb1 + hsw);
        u32x2 d1 = *(const u32x2*)(pwr + prb1 + 4 - hsw);
        u32x4 w00 = { e0[0], e0[1], d0[0], d0[1] };
        u32x4 w01 = { e1[0], e1[1], d1[0], d1[1] };
        bf16x8 pf00 = __builtin_bit_cast(bf16x8, w00);
        bf16x8 pf01 = __builtin_bit_cast(bf16x8, w01);
        #pragma unroll
        for (int n = 0; n < 4; ++n) {
            bf16x4 pk = { (bf16)EXP2(t1[n][0]), (bf16)EXP2(t1[n][1]),
                          (bf16)EXP2(t1[n][2]), (bf16)EXP2(t1[n][3]) };
            *(bf16x4*)(pwr + pwa[n]) = pk;
        }
        u32x2 e2 = *(const u32x2*)(pwr + prb0 + hsw);
        u32x2 d2 = *(const u32x2*)(pwr + prb0 + 4 - hsw);
        u32x2 e3 = *(const u32x2*)(pwr + prb1 + hsw);
        u32x2 d3 = *(const u32x2*)(pwr + prb1 + 4 - hsw);
        u32x4 w10 = { e2[0], e2[1], d2[0], d2[1] };
        u32x4 w11 = { e3[0], e3[1], d3[0], d3[1] };
        bf16x8 pf10 = __builtin_bit_cast(bf16x8, w10);
        bf16x8 pf11 = __builtin_bit_cast(bf16x8, w11);

        // Phase C: denominators + PV for both sub-blocks, each V fragment read once
        __builtin_amdgcn_s_setprio(1);
        ls0 = MFMA16(pf00, ones, ls0);
        ls0 = MFMA16(pf01, ones, ls0);
        ls1 = MFMA16(pf10, ones, ls1);
        ls1 = MFMA16(pf11, ones, ls1);
        #pragma unroll
        for (int dblk = 0; dblk < 4; ++dblk) {
            int row = (dblk * 16 + la16) * 128;
            bf16x8 v0 = *(const bf16x8*)(vbp + row + cA);
            bf16x8 v1 = *(const bf16x8*)(vbp + row + cB);
            o0[dblk] = MFMA16(pf00, v0, o0[dblk]);
            o0[dblk] = MFMA16(pf01, v1, o0[dblk]);
            o1[dblk] = MFMA16(pf10, v0, o1[dblk]);
            o1[dblk] = MFMA16(pf11, v1, o1[dblk]);
        }
        __builtin_amdgcn_s_setprio(0);

        __syncthreads();
        cur ^= 1;
    }

    int b = bh >> 4, h = bh & 15;
    #pragma unroll
    for (int qh = 0; qh < 2; ++qh) {
        f32x4 ls = qh ? ls1 : ls0;
        f32x4 linv;
        for (int r = 0; r < 4; ++r) linv[r] = __builtin_amdgcn_rcpf(ls[r]);
        long srowq = (long)qt * 128 + w * 32 + qh * 16 + g4 * 4;
        #pragma unroll
        for (int dblk = 0; dblk < 4; ++dblk)
            #pragma unroll
            for (int r = 0; r < 4; ++r) {
                float ov = qh ? o1[dblk][r] : o0[dblk][r];
                Ob[((long)b * 4096 + srowq + r) * 1024 + h * 64 + dblk * 16 + la16] =
                    (bf16)(ov * linv[r]);
            }
    }
}

extern "C" void kernel_launch(void* const* d_in, const int* in_sizes, int n_in,
                              void* d_out, int out_size, void* d_ws, size_t ws_size,
                              hipStream_t stream) {
    const float* x    = (const float*)d_in[0];
    const float* Wqkv = (const float*)d_in[1];
    const float* bqkv = (const float*)d_in[2];
    const float* Wout = (const float*)d_in[3];
    const float* bout = (const float*)d_in[4];
    float* out = (float*)d_out;
    char* ws = (char*)d_ws;

    bf16* xb    = (bf16*)(ws);                 // 16 MB
    bf16* WqkvT = (bf16*)(ws + 16777216);      // 6 MB
    bf16* WoutT = (bf16*)(ws + 23068672);      // 2 MB
    bf16* Qg    = (bf16*)(ws + 25165824);      // 16 MB
    bf16* Kg    = (bf16*)(ws + 41943040);      // 16 MB
    bf16* Vt    = (bf16*)(ws + 58720256);      // 16 MB (transposed V)
    bf16* attnb = (bf16*)(ws + 75497472);      // 16 MB; also Vg scratch (dead until attn)
    bf16* Vg    = attnb;

    k_cvt<<<8192, 256, 0, stream>>>(x, xb, 2097152);
    k_transpose<<<dim3(96, 32), dim3(32, 8), 0, stream>>>(Wqkv, WqkvT, 1024, 3072);
    k_transpose<<<dim3(32, 32), dim3(32, 8), 0, stream>>>(Wout, WoutT, 1024, 1024);
    k_gemm_bt<0><<<dim3(24, 64), 256, 0, stream>>>(xb, WqkvT, 1024, bqkv, Qg, Kg, Vg, nullptr);
    k_transpose_v<<<2048, 256, 0, stream>>>(Vg, Vt);
    k_attn<<<1024, 256, 0, stream>>>(Qg, Kg, Vt, attnb);
    k_gemm_bt<1><<<dim3(8, 64), 256, 0, stream>>>(attnb, WoutT, 1024, bout, nullptr, nullptr, nullptr, out);
}

// Round 22
// 259.966 us; speedup vs baseline: 1.0294x; 1.0294x over previous
//
#include <hip/hip_runtime.h>
#include <hip/hip_bf16.h>

typedef __bf16 bf16;
typedef __bf16 bf16x8 __attribute__((ext_vector_type(8)));
typedef __bf16 bf16x4 __attribute__((ext_vector_type(4)));
typedef float f32x4 __attribute__((ext_vector_type(4)));
typedef unsigned int u32x2 __attribute__((ext_vector_type(2)));
typedef unsigned int u32x4 __attribute__((ext_vector_type(4)));

#define MFMA16(a,b,c) __builtin_amdgcn_mfma_f32_16x16x32_bf16(a,b,c,0,0,0)
#define EXP2(x) __builtin_amdgcn_exp2f(x)   // raw v_exp_f32 (1 ULP), no libm guard code

// async global->LDS, 16B per lane; LDS dest = wave-uniform base + lane*16
static __device__ __forceinline__ void gll16(const void* g, void* l) {
    __builtin_amdgcn_global_load_lds(
        (const __attribute__((address_space(1))) void*)g,
        (__attribute__((address_space(3))) void*)l, 16, 0, 0);
}

// ---------------- convert x (fp32 -> bf16) ----------------
__global__ void k_cvt(const float* __restrict__ in, bf16* __restrict__ out, int n4) {
    int i = blockIdx.x * 256 + threadIdx.x;
    if (i < n4) {
        float4 v = ((const float4*)in)[i];
        bf16x4 o = { (bf16)v.x, (bf16)v.y, (bf16)v.z, (bf16)v.w };
        *(bf16x4*)(out + (long)i * 4) = o;
    }
}

// ---------------- transpose fp32 [R][C] -> bf16 [C][R] ----------------
__global__ void k_transpose(const float* __restrict__ in, bf16* __restrict__ out, int R, int C) {
    __shared__ float t[32][33];
    int c0 = blockIdx.x * 32, r0 = blockIdx.y * 32;
    int tx = threadIdx.x, ty = threadIdx.y; // 32 x 8
    for (int j = 0; j < 4; ++j)
        t[ty + 8 * j][tx] = in[(long)(r0 + ty + 8 * j) * C + c0 + tx];
    __syncthreads();
    for (int j = 0; j < 4; ++j)
        out[(long)(c0 + ty + 8 * j) * R + r0 + tx] = (bf16)t[tx][ty + 8 * j];
}

// ---------------- transpose V bf16 [BH][4096][64] -> [BH][64][4096] ----------------
__global__ void k_transpose_v(const bf16* __restrict__ in, bf16* __restrict__ out) {
    __shared__ bf16 t[64][72];
    int bh = blockIdx.x >> 6, s0 = (blockIdx.x & 63) * 64;
    int tid = threadIdx.x;
    int r = tid >> 3, c8 = (tid & 7) * 8;
    const bf16* ip = in + ((long)bh * 4096 + s0) * 64;
    *(bf16x8*)&t[r][c8]      = *(const bf16x8*)(ip + (long)r * 64 + c8);
    *(bf16x8*)&t[r + 32][c8] = *(const bf16x8*)(ip + (long)(r + 32) * 64 + c8);
    __syncthreads();
    bf16* op = out + (long)bh * 64 * 4096 + s0;
    #pragma unroll
    for (int it = 0; it < 2; ++it) {
        int d = r + it * 32;
        bf16x8 v;
        #pragma unroll
        for (int j = 0; j < 8; ++j) v[j] = t[c8 + j][d];
        *(bf16x8*)(op + (long)d * 4096 + c8) = v;
    }
}

// ---------------- GEMM C = A * B^T (reg-staged double-buffered LDS + XCD swizzle) ----------------
// MODE 0: QKV epilogue -> Qg (scaled 0.125*log2e), Kg, Vg all [B,H,S,D] coalesced.
// MODE 1: out epilogue (bias, fp32 row-major). Grid must be divisible by 8.
template <int MODE>
__launch_bounds__(256)
__global__ void k_gemm_bt(const bf16* __restrict__ A, const bf16* __restrict__ BT, int K,
                          const float* __restrict__ bias,
                          bf16* __restrict__ Qg, bf16* __restrict__ Kg, bf16* __restrict__ Vg,
                          float* __restrict__ Out) {
    __shared__ bf16 As[2][128][40];
    __shared__ bf16 Bs[2][128][40];
    int tid = threadIdx.x;
    int w = tid >> 6, lane = tid & 63;
    // XCD-aware bijective block swizzle (T1): nwg % 8 == 0 for both launches
    int nwg = gridDim.x * gridDim.y;
    int wg0 = blockIdx.y * gridDim.x + blockIdx.x;
    int sw = (wg0 & 7) * (nwg >> 3) + (wg0 >> 3);
    int bx = sw % gridDim.x, by = sw / gridDim.x;
    int m0 = by * 128, n0 = bx * 128;
    int wm = (w >> 1) * 64, wn = (w & 1) * 64;
    f32x4 acc[4][4] = {};
    int srow = tid >> 1, scol = (tid & 1) * 16;
    const bf16* ap = A + (long)(m0 + srow) * K + scol;
    const bf16* bp = BT + (long)(n0 + srow) * K + scol;
    int la = lane & 15, g8 = (lane >> 4) * 8;

    {   // preload slab 0
        bf16x8 a0 = *(const bf16x8*)(ap);
        bf16x8 a1 = *(const bf16x8*)(ap + 8);
        bf16x8 b0 = *(const bf16x8*)(bp);
        bf16x8 b1 = *(const bf16x8*)(bp + 8);
        *(bf16x8*)&As[0][srow][scol] = a0;
        *(bf16x8*)&As[0][srow][scol + 8] = a1;
        *(bf16x8*)&Bs[0][srow][scol] = b0;
        *(bf16x8*)&Bs[0][srow][scol + 8] = b1;
    }
    __syncthreads();

    int cur = 0;
    for (int kk = 0; kk < K; kk += 32) {
        bf16x8 a0, a1, b0, b1;
        bool more = (kk + 32) < K;
        if (more) {
            a0 = *(const bf16x8*)(ap + kk + 32);
            a1 = *(const bf16x8*)(ap + kk + 40);
            b0 = *(const bf16x8*)(bp + kk + 32);
            b1 = *(const bf16x8*)(bp + kk + 40);
        }
        bf16x8 af[4], bfv[4];
        for (int i = 0; i < 4; ++i) af[i] = *(const bf16x8*)&As[cur][wm + i * 16 + la][g8];
        for (int i = 0; i < 4; ++i) bfv[i] = *(const bf16x8*)&Bs[cur][wn + i * 16 + la][g8];
        for (int i = 0; i < 4; ++i)
            for (int j = 0; j < 4; ++j)
                acc[i][j] = MFMA16(af[i], bfv[j], acc[i][j]);
        if (more) {
            *(bf16x8*)&As[cur ^ 1][srow][scol] = a0;
            *(bf16x8*)&As[cur ^ 1][srow][scol + 8] = a1;
            *(bf16x8*)&Bs[cur ^ 1][srow][scol] = b0;
            *(bf16x8*)&Bs[cur ^ 1][srow][scol + 8] = b1;
        }
        __syncthreads();
        cur ^= 1;
    }

    for (int j = 0; j < 4; ++j) {
        int n = n0 + wn + j * 16 + la;
        float bb = bias[n];
        if (MODE == 0) {
            int which = n >> 10, e = n & 1023, h = e >> 6, d = e & 63;
            for (int i = 0; i < 4; ++i) {
                int mbase = m0 + wm + i * 16 + (lane >> 4) * 4;
                for (int r = 0; r < 4; ++r) {
                    int m = mbase + r;
                    float v = acc[i][j][r] + bb;
                    int b = m >> 12, s = m & 4095;
                    long bhh = (long)(b * 16 + h);
                    if (which == 0)      Qg[(bhh * 4096 + s) * 64 + d] = (bf16)(v * 0.18033688f); // 0.125*log2e
                    else if (which == 1) Kg[(bhh * 4096 + s) * 64 + d] = (bf16)v;
                    else                 Vg[(bhh * 4096 + s) * 64 + d] = (bf16)v;
                }
            }
        } else {
            for (int i = 0; i < 4; ++i) {
                int mbase = m0 + wm + i * 16 + (lane >> 4) * 4;
                for (int r = 0; r < 4; ++r)
                    Out[(long)(mbase + r) * 1024 + n] = acc[i][j][r] + bb;
            }
        }
    }
}

// ---------------- flash attention (round-20-identical) ----------------
__launch_bounds__(256, 4)
__global__ void k_attn(const bf16* __restrict__ Qg, const bf16* __restrict__ Kg,
                       const bf16* __restrict__ Vt, bf16* __restrict__ Ob) {
    __shared__ __align__(16) char lds[32768];   // [2 bufs][K 8KB | V 8KB]
    __shared__ __align__(16) bf16 Pl[4][16][64];
    int wg = blockIdx.x;
    int swz = (wg & 7) * 128 + (wg >> 3);       // bijective: 1024 = 8*128
    int bh = swz >> 5, qt = swz & 31;
    int tid = threadIdx.x, w = tid >> 6, lane = tid & 63;
    int la16 = lane & 15, g4 = lane >> 4, g8 = g4 * 8;

    const bf16* Kbase = Kg + (long)bh * 4096 * 64;
    const bf16* Vbase = Vt + (long)bh * 64 * 4096;
    const bf16* Qp = Qg + ((long)bh * 4096 + qt * 128 + w * 32 + la16) * 64;
    bf16x8 qA0 = *(const bf16x8*)(Qp + g8);
    bf16x8 qA1 = *(const bf16x8*)(Qp + 32 + g8);
    bf16x8 qB0 = *(const bf16x8*)(Qp + 1024 + g8);
    bf16x8 qB1 = *(const bf16x8*)(Qp + 1024 + 32 + g8);

    int srow = tid >> 3, sc = tid & 7;
    int csw = sc ^ (srow & 7);
    const bf16* kg = Kbase + (long)srow * 64 + csw * 8;
    const bf16* vg = Vbase + (long)srow * 4096 + csw * 8;
    int wseg = w * 1024;

    int x7 = la16 & 7;
    int bit3 = la16 >> 3;
    int hsw = bit3 * 4;              // element offset of even-kb half within its chunk
    int cA = (g4 ^ x7) << 4;
    int cB = ((4 + g4) ^ x7) << 4;

    const bf16 one = (bf16)1.0f;
    bf16x8 ones = { one, one, one, one, one, one, one, one };

    // P store addresses (one b64 per n): kb = 4n+g4 -> chunk (2n+(g4>>1))^x7, half (g4&1)^bit3
    int pwa[4];
    #pragma unroll
    for (int n = 0; n < 4; ++n)
        pwa[n] = la16 * 64 + (((2 * n + (g4 >> 1)) ^ x7) << 3) + ((g4 & 1) ^ bit3) * 4;
    bf16* pwr = &Pl[w][0][0];
    int prb0 = la16 * 64 + ((g4 ^ x7) << 3);
    int prb1 = la16 * 64 + (((4 + g4) ^ x7) << 3);

    f32x4 o0[4] = {}, o1[4] = {};
    f32x4 ls0 = {}, ls1 = {};

    gll16(kg, lds + wseg);
    gll16(kg + 2048, lds + 4096 + wseg);
    gll16(vg, lds + 8192 + wseg);
    gll16(vg + 131072, lds + 12288 + wseg);
    __syncthreads();

    int cur = 0;
    for (int kv0 = 0; kv0 < 4096; kv0 += 64) {
        bool more = (kv0 + 64) < 4096;
        if (more) {
            char* dbuf = lds + (cur ^ 1) * 16384;
            long kOff = (long)(kv0 + 64) * 64;
            gll16(kg + kOff, dbuf + wseg);
            gll16(kg + kOff + 2048, dbuf + 4096 + wseg);
            gll16(vg + (kv0 + 64), dbuf + 8192 + wseg);
            gll16(vg + (kv0 + 64) + 131072, dbuf + 12288 + wseg);
        }
        const char* kb = lds + cur * 16384;
        const char* vbp = kb + 8192;

        // Phase A: S^T = K x Q^T for both sub-blocks (each K fragment read once)
        f32x4 t0[4] = {}, t1[4] = {};
        __builtin_amdgcn_s_setprio(1);
        #pragma unroll
        for (int n = 0; n < 4; ++n) {
            int row = (n * 16 + la16) * 128;
            bf16x8 k0 = *(const bf16x8*)(kb + row + cA);
            bf16x8 k1 = *(const bf16x8*)(kb + row + cB);
            t0[n] = MFMA16(k0, qA0, t0[n]);
            t0[n] = MFMA16(k1, qA1, t0[n]);
            t1[n] = MFMA16(k0, qB0, t1[n]);
            t1[n] = MFMA16(k1, qB1, t1[n]);
        }
        __builtin_amdgcn_s_setprio(0);

        // Phase B: P = exp2(s) (raw v_exp_f32) -> one b64 store per n; frags via two b64 reads
        #pragma unroll
        for (int n = 0; n < 4; ++n) {
            bf16x4 pk = { (bf16)EXP2(t0[n][0]), (bf16)EXP2(t0[n][1]),
                          (bf16)EXP2(t0[n][2]), (bf16)EXP2(t0[n][3]) };
            *(bf16x4*)(pwr + pwa[n]) = pk;
        }
        u32x2 e0 = *(const u32x2*)(pwr + prb0 + hsw);
        u32x2 d0 = *(const u32x2*)(pwr + prb0 + 4 - hsw);
        u32x2 e1 = *(const u32x2*)(pwr + prb1 + hsw);
        u32x2 d1 = *(const u32x2*)(pwr + prb1 + 4 - hsw);
        u32x4 w00 = { e0[0], e0[1], d0[0], d0[1] };
        u32x4 w01 = { e1[0], e1[1], d1[0], d1[1] };
        bf16x8 pf00 = __builtin_bit_cast(bf16x8, w00);
        bf16x8 pf01 = __builtin_bit_cast(bf16x8, w01);
        #pragma unroll
        for (int n = 0; n < 4; ++n) {
            bf16x4 pk = { (bf16)EXP2(t1[n][0]), (bf16)EXP2(t1[n][1]),
                          (bf16)EXP2(t1[n][2]), (bf16)EXP2(t1[n][3]) };
            *(bf16x4*)(pwr + pwa[n]) = pk;
        }
        u32x2 e2 = *(const u32x2*)(pwr + prb0 + hsw);
        u32x2 d2 = *(const u32x2*)(pwr + prb0 + 4 - hsw);
        u32x2 e3 = *(const u32x2*)(pwr + prb1 + hsw);
        u32x2 d3 = *(const u32x2*)(pwr + prb1 + 4 - hsw);
        u32x4 w10 = { e2[0], e2[1], d2[0], d2[1] };
        u32x4 w11 = { e3[0], e3[1], d3[0], d3[1] };
        bf16x8 pf10 = __builtin_bit_cast(bf16x8, w10);
        bf16x8 pf11 = __builtin_bit_cast(bf16x8, w11);

        // Phase C: denominators + PV for both sub-blocks, each V fragment read once
        __builtin_amdgcn_s_setprio(1);
        ls0 = MFMA16(pf00, ones, ls0);
        ls0 = MFMA16(pf01, ones, ls0);
        ls1 = MFMA16(pf10, ones, ls1);
        ls1 = MFMA16(pf11, ones, ls1);
        #pragma unroll
        for (int dblk = 0; dblk < 4; ++dblk) {
            int row = (dblk * 16 + la16) * 128;
            bf16x8 v0 = *(const bf16x8*)(vbp + row + cA);
            bf16x8 v1 = *(const bf16x8*)(vbp + row + cB);
            o0[dblk] = MFMA16(pf00, v0, o0[dblk]);
            o0[dblk] = MFMA16(pf01, v1, o0[dblk]);
            o1[dblk] = MFMA16(pf10, v0, o1[dblk]);
            o1[dblk] = MFMA16(pf11, v1, o1[dblk]);
        }
        __builtin_amdgcn_s_setprio(0);

        __syncthreads();
        cur ^= 1;
    }

    int b = bh >> 4, h = bh & 15;
    #pragma unroll
    for (int qh = 0; qh < 2; ++qh) {
        f32x4 ls = qh ? ls1 : ls0;
        f32x4 linv;
        for (int r = 0; r < 4; ++r) linv[r] = __builtin_amdgcn_rcpf(ls[r]);
        long srowq = (long)qt * 128 + w * 32 + qh * 16 + g4 * 4;
        #pragma unroll
        for (int dblk = 0; dblk < 4; ++dblk)
            #pragma unroll
            for (int r = 0; r < 4; ++r) {
                float ov = qh ? o1[dblk][r] : o0[dblk][r];
                Ob[((long)b * 4096 + srowq + r) * 1024 + h * 64 + dblk * 16 + la16] =
                    (bf16)(ov * linv[r]);
            }
    }
}

extern "C" void kernel_launch(void* const* d_in, const int* in_sizes, int n_in,
                              void* d_out, int out_size, void* d_ws, size_t ws_size,
                              hipStream_t stream) {
    const float* x    = (const float*)d_in[0];
    const float* Wqkv = (const float*)d_in[1];
    const float* bqkv = (const float*)d_in[2];
    const float* Wout = (const float*)d_in[3];
    const float* bout = (const float*)d_in[4];
    float* out = (float*)d_out;
    char* ws = (char*)d_ws;

    bf16* xb    = (bf16*)(ws);                 // 16 MB
    bf16* WqkvT = (bf16*)(ws + 16777216);      // 6 MB
    bf16* WoutT = (bf16*)(ws + 23068672);      // 2 MB
    bf16* Qg    = (bf16*)(ws + 25165824);      // 16 MB
    bf16* Kg    = (bf16*)(ws + 41943040);      // 16 MB
    bf16* Vt    = (bf16*)(ws + 58720256);      // 16 MB (transposed V)
    bf16* attnb = (bf16*)(ws + 75497472);      // 16 MB; also Vg scratch (dead until attn)
    bf16* Vg    = attnb;

    k_cvt<<<8192, 256, 0, stream>>>(x, xb, 2097152);
    k_transpose<<<dim3(96, 32), dim3(32, 8), 0, stream>>>(Wqkv, WqkvT, 1024, 3072);
    k_transpose<<<dim3(32, 32), dim3(32, 8), 0, stream>>>(Wout, WoutT, 1024, 1024);
    k_gemm_bt<0><<<dim3(24, 64), 256, 0, stream>>>(xb, WqkvT, 1024, bqkv, Qg, Kg, Vg, nullptr);
    k_transpose_v<<<2048, 256, 0, stream>>>(Vg, Vt);
    k_attn<<<1024, 256, 0, stream>>>(Qg, Kg, Vt, attnb);
    k_gemm_bt<1><<<dim3(8, 64), 256, 0, stream>>>(attnb, WoutT, 1024, bout, nullptr, nullptr, nullptr, out);
}